// Round 1
// baseline (173.888 us; speedup 1.0000x reference)
//
#include <hip/hip_runtime.h>
#include <math.h>

// Neural-ODE RK45 (Dormand-Prince), one thread per batch element.
// Encoder branch of the reference is dead code (alpha/beta unused) -> skipped.
// Per-element early exit: once rem <= 1e-8 the reference state is frozen, so
// breaking out is bit-equivalent to running the remaining lockstep steps.

#define MAXS 96

__device__ __forceinline__ void f_eval(float t, float y0, float y1,
    const float* __restrict__ w1, const float* __restrict__ b1,
    const float* __restrict__ w2, const float* __restrict__ b2,
    const float* __restrict__ w3, const float* __restrict__ b3,
    float& o0, float& o1)
{
    // layer 1: 3 -> 32, relu. Weight indices uniform across lanes -> s_load.
    float h1[32];
#pragma unroll
    for (int j = 0; j < 32; ++j) {
        float v = fmaf(t, w1[j], fmaf(y0, w1[32 + j], fmaf(y1, w1[64 + j], b1[j])));
        h1[j] = fmaxf(v, 0.0f);
    }
    // layer 2: 32 -> 32, relu. j-loop fully unrolled -> 32 independent
    // accumulator chains (plenty of ILP to hide the 4-cyc FMA latency).
    float h2[32];
#pragma unroll
    for (int j = 0; j < 32; ++j) h2[j] = b2[j];
#pragma unroll 4
    for (int i = 0; i < 32; ++i) {
        float hi = h1[i];
        const float* __restrict__ row = w2 + i * 32;
#pragma unroll
        for (int j = 0; j < 32; ++j) h2[j] = fmaf(hi, row[j], h2[j]);
    }
    // layer 3: 32 -> 2 (relu applied to h2 here)
    float a0 = b3[0], a1 = b3[1];
#pragma unroll
    for (int i = 0; i < 32; ++i) {
        float hv = fmaxf(h2[i], 0.0f);
        a0 = fmaf(hv, w3[2 * i + 0], a0);
        a1 = fmaf(hv, w3[2 * i + 1], a1);
    }
    o0 = a0; o1 = a1;
}

__global__ __launch_bounds__(64) void node_kernel(
    const float* __restrict__ x, const float* __restrict__ samples,
    const float* __restrict__ w1, const float* __restrict__ b1,
    const float* __restrict__ w2, const float* __restrict__ b2,
    const float* __restrict__ w3, const float* __restrict__ b3,
    const float* __restrict__ fcw, const float* __restrict__ fcb,
    float* __restrict__ out, int n)
{
    int idx = blockIdx.x * blockDim.x + threadIdx.x;
    if (idx >= n) return;

    float y0 = x[2 * idx + 0];
    float y1 = x[2 * idx + 1];
    float T  = fminf(samples[idx], 50.0f);
    float t  = 0.0f;
    float h  = 0.05f;

    for (int s = 0; s < MAXS; ++s) {
        float rem = T - t;
        if (!(rem > 1e-8f)) break;           // state frozen from here on
        float hs = fminf(h, rem);

        float k10, k11, k20, k21, k30, k31, k40, k41, k50, k51, k60, k61, k70, k71;
        float u0, u1;

        f_eval(t, y0, y1, w1, b1, w2, b2, w3, b3, k10, k11);

        u0 = y0 + hs * (0.2f * k10);
        u1 = y1 + hs * (0.2f * k11);
        f_eval(t + hs * 0.2f, u0, u1, w1, b1, w2, b2, w3, b3, k20, k21);

        u0 = y0 + hs * ((float)(3.0/40.0) * k10 + (float)(9.0/40.0) * k20);
        u1 = y1 + hs * ((float)(3.0/40.0) * k11 + (float)(9.0/40.0) * k21);
        f_eval(t + hs * 0.3f, u0, u1, w1, b1, w2, b2, w3, b3, k30, k31);

        u0 = y0 + hs * ((float)(44.0/45.0) * k10 - (float)(56.0/15.0) * k20 + (float)(32.0/9.0) * k30);
        u1 = y1 + hs * ((float)(44.0/45.0) * k11 - (float)(56.0/15.0) * k21 + (float)(32.0/9.0) * k31);
        f_eval(t + hs * 0.8f, u0, u1, w1, b1, w2, b2, w3, b3, k40, k41);

        u0 = y0 + hs * ((float)(19372.0/6561.0) * k10 - (float)(25360.0/2187.0) * k20
                      + (float)(64448.0/6561.0) * k30 - (float)(212.0/729.0) * k40);
        u1 = y1 + hs * ((float)(19372.0/6561.0) * k11 - (float)(25360.0/2187.0) * k21
                      + (float)(64448.0/6561.0) * k31 - (float)(212.0/729.0) * k41);
        f_eval(t + hs * (float)(8.0/9.0), u0, u1, w1, b1, w2, b2, w3, b3, k50, k51);

        u0 = y0 + hs * ((float)(9017.0/3168.0) * k10 - (float)(355.0/33.0) * k20
                      + (float)(46732.0/5247.0) * k30 + (float)(49.0/176.0) * k40
                      - (float)(5103.0/18656.0) * k50);
        u1 = y1 + hs * ((float)(9017.0/3168.0) * k11 - (float)(355.0/33.0) * k21
                      + (float)(46732.0/5247.0) * k31 + (float)(49.0/176.0) * k41
                      - (float)(5103.0/18656.0) * k51);
        f_eval(t + hs, u0, u1, w1, b1, w2, b2, w3, b3, k60, k61);

        float y50 = y0 + hs * ((float)(35.0/384.0) * k10 + (float)(500.0/1113.0) * k30
                             + (float)(125.0/192.0) * k40 - (float)(2187.0/6784.0) * k50
                             + (float)(11.0/84.0) * k60);
        float y51 = y1 + hs * ((float)(35.0/384.0) * k11 + (float)(500.0/1113.0) * k31
                             + (float)(125.0/192.0) * k41 - (float)(2187.0/6784.0) * k51
                             + (float)(11.0/84.0) * k61);
        f_eval(t + hs, y50, y51, w1, b1, w2, b2, w3, b3, k70, k71);

        float e0 = hs * ((float)(71.0/57600.0) * k10 - (float)(71.0/16695.0) * k30
                       + (float)(71.0/1920.0) * k40 - (float)(17253.0/339200.0) * k50
                       + (float)(22.0/525.0) * k60 - (float)(1.0/40.0) * k70);
        float e1 = hs * ((float)(71.0/57600.0) * k11 - (float)(71.0/16695.0) * k31
                       + (float)(71.0/1920.0) * k41 - (float)(17253.0/339200.0) * k51
                       + (float)(22.0/525.0) * k61 - (float)(1.0/40.0) * k71);

        float sc0 = 0.01f + 0.01f * fmaxf(fabsf(y0), fabsf(y50));
        float sc1 = 0.01f + 0.01f * fmaxf(fabsf(y1), fabsf(y51));
        float r0 = e0 / sc0, r1 = e1 / sc1;
        float en = sqrtf(0.5f * (r0 * r0 + r1 * r1));

        float fac = 0.9f * powf(fmaxf(en, 1e-10f), -0.2f);
        fac = fminf(fmaxf(fac, 0.2f), 10.0f);

        if (en <= 1.0f) { t += hs; y0 = y50; y1 = y51; }
        h = hs * fac;
    }

    // final head: y @ fc_w (2x10) + fc_b
#pragma unroll
    for (int c = 0; c < 10; ++c) {
        out[10 * idx + c] = fmaf(y0, fcw[c], fmaf(y1, fcw[10 + c], fcb[c]));
    }
}

extern "C" void kernel_launch(void* const* d_in, const int* in_sizes, int n_in,
                              void* d_out, int out_size, void* d_ws, size_t ws_size,
                              hipStream_t stream) {
    const float* x   = (const float*)d_in[0];
    const float* sm  = (const float*)d_in[1];
    const float* w1  = (const float*)d_in[2];
    const float* b1  = (const float*)d_in[3];
    const float* w2  = (const float*)d_in[4];
    const float* b2  = (const float*)d_in[5];
    const float* w3  = (const float*)d_in[6];
    const float* b3  = (const float*)d_in[7];
    const float* fcw = (const float*)d_in[8];
    const float* fcb = (const float*)d_in[9];
    // d_in[10..15] = enc_* : dead code in the reference, unused.
    float* out = (float*)d_out;

    int n = in_sizes[1];                 // B (samples has B elements)
    const int block = 64;                // 1 wave/block -> spread over all 256 CUs
    int grid = (n + block - 1) / block;  // 256 blocks
    node_kernel<<<grid, block, 0, stream>>>(x, sm, w1, b1, w2, b2, w3, b3,
                                            fcw, fcb, out, n);
}

// Round 2
// 114.028 us; speedup vs baseline: 1.5250x; 1.5250x over previous
//
#include <hip/hip_runtime.h>
#include <math.h>

// Neural-ODE RK45, 8 lanes per batch element (j-split of the 32-wide hidden).
// Lane m of each aligned 8-lane group owns output columns [4m, 4m+4) of
// layer1/layer2; w2[:, 4m:4m+4] lives in 128 VGPRs (loaded once). Layer-2
// input (all 32 h1) is all-gathered with ds_bpermute shuffles; layer-3 is an
// 8-lane butterfly all-reduce (bitwise-uniform across the group, so RK45
// control flow stays group-coherent). 131072 threads = 2048 waves = 2/SIMD.

#define MAXS 96

__global__ __launch_bounds__(256, 2) void node_kernel(
    const float* __restrict__ x, const float* __restrict__ samples,
    const float* __restrict__ w1, const float* __restrict__ b1,
    const float* __restrict__ w2, const float* __restrict__ b2,
    const float* __restrict__ w3, const float* __restrict__ b3,
    const float* __restrict__ fcw, const float* __restrict__ fcb,
    float* __restrict__ out, int n)
{
    const int tid  = blockIdx.x * blockDim.x + threadIdx.x;
    const int elem = tid >> 3;
    const int m    = tid & 7;
    if (elem >= n) return;

    const int lane = threadIdx.x & 63;
    const int gbase = lane & ~7;          // first lane of this 8-lane group

    // ---- preload this lane's weight slices into registers (once) ----
    const float4* w1v = (const float4*)w1;   // (3,32) row-major
    const float4* b1v = (const float4*)b1;
    const float4* w2v = (const float4*)w2;   // (32,32) row-major
    const float4* b2v = (const float4*)b2;
    const float4* w3v = (const float4*)w3;   // (32,2) row-major

    const float4 w1c0 = w1v[0 * 8 + m];      // w1[0][4m..4m+4)
    const float4 w1c1 = w1v[1 * 8 + m];
    const float4 w1c2 = w1v[2 * 8 + m];
    const float4 b1c  = b1v[m];
    const float4 b2c  = b2v[m];
    const float4 w3a  = w3v[2 * m + 0];      // rows 4m,4m+1 of w3 (pairs)
    const float4 w3b  = w3v[2 * m + 1];      // rows 4m+2,4m+3
    const float  b30  = b3[0], b31 = b3[1];

    float4 w2c[32];                           // w2[i][4m..4m+4) for all i
#pragma unroll
    for (int i = 0; i < 32; ++i) w2c[i] = w2v[i * 8 + m];

    float y0 = x[2 * elem + 0];
    float y1 = x[2 * elem + 1];
    float T  = fminf(samples[elem], 50.0f);
    float t  = 0.0f;
    float h  = 0.05f;

    // f(t, y) -> (o0, o1), cooperative across the 8-lane group
    auto f_eval = [&](float tt, float z0, float z1, float& o0, float& o1) {
        // layer 1: own 4 outputs, relu
        float h0 = fmaxf(fmaf(tt, w1c0.x, fmaf(z0, w1c1.x, fmaf(z1, w1c2.x, b1c.x))), 0.0f);
        float h1_ = fmaxf(fmaf(tt, w1c0.y, fmaf(z0, w1c1.y, fmaf(z1, w1c2.y, b1c.y))), 0.0f);
        float h2_ = fmaxf(fmaf(tt, w1c0.z, fmaf(z0, w1c1.z, fmaf(z1, w1c2.z, b1c.z))), 0.0f);
        float h3_ = fmaxf(fmaf(tt, w1c0.w, fmaf(z0, w1c1.w, fmaf(z1, w1c2.w, b1c.w))), 0.0f);

        // all-gather the full 32-wide h1 across the group (ds_bpermute)
        float g[32];
#pragma unroll
        for (int k = 0; k < 32; ++k) {
            float v = ((k & 3) == 0) ? h0 : ((k & 3) == 1) ? h1_
                    : ((k & 3) == 2) ? h2_ : h3_;
            g[k] = __shfl(v, gbase + (k >> 2), 64);
        }

        // layer 2: own 4 outputs, 32 FMAs each, weights in registers
        float a0 = b2c.x, a1 = b2c.y, a2 = b2c.z, a3 = b2c.w;
#pragma unroll
        for (int i = 0; i < 32; ++i) {
            a0 = fmaf(g[i], w2c[i].x, a0);
            a1 = fmaf(g[i], w2c[i].y, a1);
            a2 = fmaf(g[i], w2c[i].z, a2);
            a3 = fmaf(g[i], w2c[i].w, a3);
        }
        a0 = fmaxf(a0, 0.0f); a1 = fmaxf(a1, 0.0f);
        a2 = fmaxf(a2, 0.0f); a3 = fmaxf(a3, 0.0f);

        // layer 3: partial over own 4 rows, then butterfly all-reduce
        float p0 = fmaf(a3, w3b.z, fmaf(a2, w3b.x, fmaf(a1, w3a.z, a0 * w3a.x)));
        float p1 = fmaf(a3, w3b.w, fmaf(a2, w3b.y, fmaf(a1, w3a.w, a0 * w3a.y)));
        p0 += __shfl_xor(p0, 1, 64);  p1 += __shfl_xor(p1, 1, 64);
        p0 += __shfl_xor(p0, 2, 64);  p1 += __shfl_xor(p1, 2, 64);
        p0 += __shfl_xor(p0, 4, 64);  p1 += __shfl_xor(p1, 4, 64);
        o0 = p0 + b30;
        o1 = p1 + b31;
    };

    for (int s = 0; s < MAXS; ++s) {
        float rem = T - t;
        if (!(rem > 1e-8f)) break;             // state frozen from here on
        float hs = fminf(h, rem);

        float k10, k11, k20, k21, k30, k31, k40, k41, k50, k51, k60, k61, k70, k71;
        float u0, u1;

        f_eval(t, y0, y1, k10, k11);

        u0 = y0 + hs * (0.2f * k10);
        u1 = y1 + hs * (0.2f * k11);
        f_eval(t + hs * 0.2f, u0, u1, k20, k21);

        u0 = y0 + hs * ((float)(3.0/40.0) * k10 + (float)(9.0/40.0) * k20);
        u1 = y1 + hs * ((float)(3.0/40.0) * k11 + (float)(9.0/40.0) * k21);
        f_eval(t + hs * 0.3f, u0, u1, k30, k31);

        u0 = y0 + hs * ((float)(44.0/45.0) * k10 - (float)(56.0/15.0) * k20 + (float)(32.0/9.0) * k30);
        u1 = y1 + hs * ((float)(44.0/45.0) * k11 - (float)(56.0/15.0) * k21 + (float)(32.0/9.0) * k31);
        f_eval(t + hs * 0.8f, u0, u1, k40, k41);

        u0 = y0 + hs * ((float)(19372.0/6561.0) * k10 - (float)(25360.0/2187.0) * k20
                      + (float)(64448.0/6561.0) * k30 - (float)(212.0/729.0) * k40);
        u1 = y1 + hs * ((float)(19372.0/6561.0) * k11 - (float)(25360.0/2187.0) * k21
                      + (float)(64448.0/6561.0) * k31 - (float)(212.0/729.0) * k41);
        f_eval(t + hs * (float)(8.0/9.0), u0, u1, k50, k51);

        u0 = y0 + hs * ((float)(9017.0/3168.0) * k10 - (float)(355.0/33.0) * k20
                      + (float)(46732.0/5247.0) * k30 + (float)(49.0/176.0) * k40
                      - (float)(5103.0/18656.0) * k50);
        u1 = y1 + hs * ((float)(9017.0/3168.0) * k11 - (float)(355.0/33.0) * k21
                      + (float)(46732.0/5247.0) * k31 + (float)(49.0/176.0) * k41
                      - (float)(5103.0/18656.0) * k51);
        f_eval(t + hs, u0, u1, k60, k61);

        float y50 = y0 + hs * ((float)(35.0/384.0) * k10 + (float)(500.0/1113.0) * k30
                             + (float)(125.0/192.0) * k40 - (float)(2187.0/6784.0) * k50
                             + (float)(11.0/84.0) * k60);
        float y51 = y1 + hs * ((float)(35.0/384.0) * k11 + (float)(500.0/1113.0) * k31
                             + (float)(125.0/192.0) * k41 - (float)(2187.0/6784.0) * k51
                             + (float)(11.0/84.0) * k61);
        f_eval(t + hs, y50, y51, k70, k71);

        float e0 = hs * ((float)(71.0/57600.0) * k10 - (float)(71.0/16695.0) * k30
                       + (float)(71.0/1920.0) * k40 - (float)(17253.0/339200.0) * k50
                       + (float)(22.0/525.0) * k60 - (float)(1.0/40.0) * k70);
        float e1 = hs * ((float)(71.0/57600.0) * k11 - (float)(71.0/16695.0) * k31
                       + (float)(71.0/1920.0) * k41 - (float)(17253.0/339200.0) * k51
                       + (float)(22.0/525.0) * k61 - (float)(1.0/40.0) * k71);

        float sc0 = 0.01f + 0.01f * fmaxf(fabsf(y0), fabsf(y50));
        float sc1 = 0.01f + 0.01f * fmaxf(fabsf(y1), fabsf(y51));
        float r0 = e0 / sc0, r1 = e1 / sc1;
        float en = sqrtf(0.5f * (r0 * r0 + r1 * r1));

        float fac = 0.9f * powf(fmaxf(en, 1e-10f), -0.2f);
        fac = fminf(fmaxf(fac, 0.2f), 10.0f);

        if (en <= 1.0f) { t += hs; y0 = y50; y1 = y51; }
        h = hs * fac;
    }

    // final head: y @ fc_w (2x10) + fc_b; all 8 lanes hold identical y.
    {
        int c = m;
        out[10 * elem + c] = fmaf(y0, fcw[c], fmaf(y1, fcw[10 + c], fcb[c]));
        if (m < 2) {
            int c2 = 8 + m;
            out[10 * elem + c2] = fmaf(y0, fcw[c2], fmaf(y1, fcw[10 + c2], fcb[c2]));
        }
    }
}

extern "C" void kernel_launch(void* const* d_in, const int* in_sizes, int n_in,
                              void* d_out, int out_size, void* d_ws, size_t ws_size,
                              hipStream_t stream) {
    const float* x   = (const float*)d_in[0];
    const float* sm  = (const float*)d_in[1];
    const float* w1  = (const float*)d_in[2];
    const float* b1  = (const float*)d_in[3];
    const float* w2  = (const float*)d_in[4];
    const float* b2  = (const float*)d_in[5];
    const float* w3  = (const float*)d_in[6];
    const float* b3  = (const float*)d_in[7];
    const float* fcw = (const float*)d_in[8];
    const float* fcb = (const float*)d_in[9];
    // d_in[10..15] = enc_* : dead code in the reference, unused.
    float* out = (float*)d_out;

    int n = in_sizes[1];                       // B
    const int block = 256;                     // 4 waves/block, 2 blocks/CU
    int threads = n * 8;                       // 8 lanes per element
    int grid = (threads + block - 1) / block;  // 512 blocks
    node_kernel<<<grid, block, 0, stream>>>(x, sm, w1, b1, w2, b2, w3, b3,
                                            fcw, fcb, out, n);
}

// Round 3
// 111.034 us; speedup vs baseline: 1.5661x; 1.0270x over previous
//
#include <hip/hip_runtime.h>
#include <math.h>

// Neural-ODE RK45, 16 lanes per batch element.
// Lane m (= lane & 15) owns hidden columns {2m, 2m+1} of layer1/layer2
// (w2[:, 2m:2m+2] = 64 VGPRs, loaded once) and rows {2m, 2m+1} of layer3.
// All math is 2-wide packed fp32 (v_pk_fma_f32 via ext_vector + elementwise
// builtins): the 2 owned columns / the 2 ODE state components share one
// instruction. Cross-lane traffic uses ds_swizzle with compile-time
// patterns (no index-VGPR setup):
//   broadcast lane j of 16-group : (j<<5) | 0x10   (and=0x10 keeps bit4)
//   butterfly xor X              : (X<<10) | 0x1f
// The 16-lane group is bitwise-uniform in RK state, so control flow is
// group-coherent. 262144 threads = 4096 waves; ~150 VGPR -> 3 waves/SIMD.

#define MAXS 96

typedef float v2f __attribute__((ext_vector_type(2)));

static __device__ __forceinline__ v2f splat(float s) { v2f v; v.x = s; v.y = s; return v; }
static __device__ __forceinline__ v2f vfma(v2f a, v2f b, v2f c) { return __builtin_elementwise_fma(a, b, c); }
static __device__ __forceinline__ v2f vrelu(v2f a) { return __builtin_elementwise_max(a, splat(0.0f)); }

template<int PAT>
static __device__ __forceinline__ float swzf(float x) {
    return __int_as_float(__builtin_amdgcn_ds_swizzle(__float_as_int(x), PAT));
}

// gather h1[2j], h1[2j+1] from lane j of the 16-lane group
#define GATH(j)  g[2*(j)]   = swzf<(((j) << 5) | 0x10)>(hx); \
                 g[2*(j)+1] = swzf<(((j) << 5) | 0x10)>(hy)

template<int X>
static __device__ __forceinline__ v2f redstage(v2f p) {
    v2f q; q.x = swzf<((X << 10) | 0x1f)>(p.x); q.y = swzf<((X << 10) | 0x1f)>(p.y);
    return p + q;
}

__global__ __launch_bounds__(256, 3) void node_kernel(
    const float* __restrict__ x, const float* __restrict__ samples,
    const float* __restrict__ w1, const float* __restrict__ b1,
    const float* __restrict__ w2, const float* __restrict__ b2,
    const float* __restrict__ w3, const float* __restrict__ b3,
    const float* __restrict__ fcw, const float* __restrict__ fcb,
    float* __restrict__ out, int n)
{
    const int tid  = blockIdx.x * blockDim.x + threadIdx.x;
    const int elem = tid >> 4;
    const int m    = tid & 15;
    if (elem >= n) return;

    // ---- preload this lane's weight slices (float2 views, once) ----
    const v2f* w1v = (const v2f*)w1;   // (3,32) row-major -> 16 pairs/row
    const v2f* b1v = (const v2f*)b1;
    const v2f* w2v = (const v2f*)w2;   // (32,32) row-major
    const v2f* b2v = (const v2f*)b2;
    const v2f* w3v = (const v2f*)w3;   // (32,2) row-major -> row r = w3v[r]

    const v2f w1r0 = w1v[0 * 16 + m];  // w1[0][2m:2m+2]
    const v2f w1r1 = w1v[1 * 16 + m];
    const v2f w1r2 = w1v[2 * 16 + m];
    const v2f b1c  = b1v[m];
    const v2f b2c  = b2v[m];
    const v2f w3r0 = w3v[2 * m + 0];   // full row 2m   of w3 (both outputs)
    const v2f w3r1 = w3v[2 * m + 1];   // full row 2m+1
    const v2f b3c  = { b3[0], b3[1] };

    v2f w2c[32];                       // w2[i][2m:2m+2] for all i
#pragma unroll
    for (int i = 0; i < 32; ++i) w2c[i] = w2v[i * 16 + m];

    v2f y = ((const v2f*)x)[elem];     // ODE state (y0, y1)
    float T = fminf(samples[elem], 50.0f);
    float t = 0.0f;
    float h = 0.05f;

    // f(t, y) -> v2f, cooperative across the 16-lane group
    auto f_eval = [&](float tt, v2f z) -> v2f {
        // layer 1: own 2 columns, relu (packed)
        v2f hv = vfma(splat(tt), w1r0, vfma(splat(z.x), w1r1,
                 vfma(splat(z.y), w1r2, b1c)));
        hv = vrelu(hv);
        float hx = hv.x, hy = hv.y;

        // all-gather the 32-wide h1 across the group (32 ds_swizzle)
        float g[32];
        GATH(0);  GATH(1);  GATH(2);  GATH(3);
        GATH(4);  GATH(5);  GATH(6);  GATH(7);
        GATH(8);  GATH(9);  GATH(10); GATH(11);
        GATH(12); GATH(13); GATH(14); GATH(15);

        // layer 2: own 2 columns, 32 packed FMAs
        v2f acc = b2c;
#pragma unroll
        for (int i = 0; i < 32; ++i) acc = vfma(splat(g[i]), w2c[i], acc);
        acc = vrelu(acc);

        // layer 3: own 2 rows -> 2 packed FMAs, then 4-stage butterfly
        v2f p = vfma(splat(acc.x), w3r0, splat(acc.y) * w3r1);
        p = redstage<1>(p);
        p = redstage<2>(p);
        p = redstage<4>(p);
        p = redstage<8>(p);
        return p + b3c;
    };

    for (int s = 0; s < MAXS; ++s) {
        float rem = T - t;
        if (!(rem > 1e-8f)) break;              // state frozen from here on
        float hs = fminf(h, rem);
        v2f hb = splat(hs);

        v2f k1 = f_eval(t, y);
        v2f k2 = f_eval(t + hs * 0.2f, vfma(hb, splat(0.2f) * k1, y));
        v2f k3 = f_eval(t + hs * 0.3f,
                 vfma(hb, vfma(splat((float)(3.0/40.0)), k1, splat((float)(9.0/40.0)) * k2), y));
        v2f k4 = f_eval(t + hs * 0.8f,
                 vfma(hb, vfma(splat((float)(44.0/45.0)), k1,
                          vfma(splat((float)(-56.0/15.0)), k2, splat((float)(32.0/9.0)) * k3)), y));
        v2f k5 = f_eval(t + hs * (float)(8.0/9.0),
                 vfma(hb, vfma(splat((float)(19372.0/6561.0)), k1,
                          vfma(splat((float)(-25360.0/2187.0)), k2,
                          vfma(splat((float)(64448.0/6561.0)), k3,
                               splat((float)(-212.0/729.0)) * k4))), y));
        v2f k6 = f_eval(t + hs,
                 vfma(hb, vfma(splat((float)(9017.0/3168.0)), k1,
                          vfma(splat((float)(-355.0/33.0)), k2,
                          vfma(splat((float)(46732.0/5247.0)), k3,
                          vfma(splat((float)(49.0/176.0)), k4,
                               splat((float)(-5103.0/18656.0)) * k5)))), y));
        v2f y5 = vfma(hb, vfma(splat((float)(35.0/384.0)), k1,
                          vfma(splat((float)(500.0/1113.0)), k3,
                          vfma(splat((float)(125.0/192.0)), k4,
                          vfma(splat((float)(-2187.0/6784.0)), k5,
                               splat((float)(11.0/84.0)) * k6)))), y);
        v2f k7 = f_eval(t + hs, y5);

        v2f err = hb * vfma(splat((float)(71.0/57600.0)), k1,
                       vfma(splat((float)(-71.0/16695.0)), k3,
                       vfma(splat((float)(71.0/1920.0)), k4,
                       vfma(splat((float)(-17253.0/339200.0)), k5,
                       vfma(splat((float)(22.0/525.0)), k6,
                            splat((float)(-1.0/40.0)) * k7)))));

        v2f ay  = __builtin_elementwise_abs(y);
        v2f ay5 = __builtin_elementwise_abs(y5);
        v2f sc  = vfma(splat(0.01f), __builtin_elementwise_max(ay, ay5), splat(0.01f));
        v2f r   = err / sc;
        float en = sqrtf(0.5f * (r.x * r.x + r.y * r.y));

        float fac = 0.9f * powf(fmaxf(en, 1e-10f), -0.2f);
        fac = fminf(fmaxf(fac, 0.2f), 10.0f);

        if (en <= 1.0f) { t += hs; y = y5; }
        h = hs * fac;
    }

    // final head: y @ fc_w (2x10) + fc_b; all 16 lanes hold identical y.
    if (m < 10) {
        out[10 * elem + m] = fmaf(y.x, fcw[m], fmaf(y.y, fcw[10 + m], fcb[m]));
    }
}

extern "C" void kernel_launch(void* const* d_in, const int* in_sizes, int n_in,
                              void* d_out, int out_size, void* d_ws, size_t ws_size,
                              hipStream_t stream) {
    const float* x   = (const float*)d_in[0];
    const float* sm  = (const float*)d_in[1];
    const float* w1  = (const float*)d_in[2];
    const float* b1  = (const float*)d_in[3];
    const float* w2  = (const float*)d_in[4];
    const float* b2  = (const float*)d_in[5];
    const float* w3  = (const float*)d_in[6];
    const float* b3  = (const float*)d_in[7];
    const float* fcw = (const float*)d_in[8];
    const float* fcb = (const float*)d_in[9];
    // d_in[10..15] = enc_* : dead code in the reference, unused.
    float* out = (float*)d_out;

    int n = in_sizes[1];                       // B
    const int block = 256;
    long long threads = (long long)n * 16;     // 16 lanes per element
    int grid = (int)((threads + block - 1) / block);
    node_kernel<<<grid, block, 0, stream>>>(x, sm, w1, b1, w2, b2, w3, b3,
                                            fcw, fcb, out, n);
}

// Round 4
// 110.247 us; speedup vs baseline: 1.5773x; 1.0071x over previous
//
#include <hip/hip_runtime.h>
#include <math.h>

// Neural-ODE RK45, 16 lanes per batch element.
// Round-4 changes vs round 3:
//  (1) w2 column slice (and small weight slices) pinned in VGPRs via empty
//      inline-asm: round-3 disasm evidence (VGPR_Count=60 < 64 needed for
//      w2c alone) showed the compiler rematerialized the weight loads inside
//      the K-loop -> 32 L1 vector loads per f_eval. Pinning deletes them.
//  (2) FSAL: k1 of step s+1 == (accepted ? k7 : k1) of step s, bitwise.
//      7 evals/step -> 6 (+1 before the loop; every element takes >=1 step
//      since samples >= 0.001 > 1e-8).
//  (3) Layer-2 uses 4 independent accumulator chains with gathers
//      interleaved per 8-row block (chain latency 128 -> ~40 cyc).
// Cross-lane via ds_swizzle compile-time patterns:
//   broadcast lane j of 16-group : (j<<5) | 0x10
//   butterfly xor X              : (X<<10) | 0x1f

#define MAXS 96

typedef float v2f __attribute__((ext_vector_type(2)));

static __device__ __forceinline__ v2f splat(float s) { v2f v; v.x = s; v.y = s; return v; }
static __device__ __forceinline__ v2f vfma(v2f a, v2f b, v2f c) { return __builtin_elementwise_fma(a, b, c); }
static __device__ __forceinline__ v2f vrelu(v2f a) { return __builtin_elementwise_max(a, splat(0.0f)); }

template<int PAT>
static __device__ __forceinline__ float swzf(float x) {
    return __int_as_float(__builtin_amdgcn_ds_swizzle(__float_as_int(x), PAT));
}

// gather h1[2j], h1[2j+1] from lane j of the 16-lane group
#define GPAIR(j) g[2*(j)]   = swzf<(((j) << 5) | 0x10)>(hx); \
                 g[2*(j)+1] = swzf<(((j) << 5) | 0x10)>(hy)

template<int X>
static __device__ __forceinline__ v2f redstage(v2f p) {
    v2f q; q.x = swzf<((X << 10) | 0x1f)>(p.x); q.y = swzf<((X << 10) | 0x1f)>(p.y);
    return p + q;
}

__global__ __launch_bounds__(256, 3) void node_kernel(
    const float* __restrict__ x, const float* __restrict__ samples,
    const float* __restrict__ w1, const float* __restrict__ b1,
    const float* __restrict__ w2, const float* __restrict__ b2,
    const float* __restrict__ w3, const float* __restrict__ b3,
    const float* __restrict__ fcw, const float* __restrict__ fcb,
    float* __restrict__ out, int n)
{
    const int tid  = blockIdx.x * blockDim.x + threadIdx.x;
    const int elem = tid >> 4;
    const int m    = tid & 15;
    if (elem >= n) return;

    // ---- preload this lane's weight slices (once) ----
    const v2f* w1v = (const v2f*)w1;   // (3,32) row-major -> 16 pairs/row
    const v2f* b1v = (const v2f*)b1;
    const v2f* w2v = (const v2f*)w2;   // (32,32) row-major
    const v2f* b2v = (const v2f*)b2;
    const v2f* w3v = (const v2f*)w3;   // (32,2) row-major -> row r = w3v[r]

    v2f w1r0 = w1v[0 * 16 + m];        // w1[0][2m:2m+2]
    v2f w1r1 = w1v[1 * 16 + m];
    v2f w1r2 = w1v[2 * 16 + m];
    v2f b1c  = b1v[m];
    v2f b2c  = b2v[m];
    v2f w3r0 = w3v[2 * m + 0];         // full row 2m   of w3
    v2f w3r1 = w3v[2 * m + 1];         // full row 2m+1
    v2f b3c  = { b3[0], b3[1] };

    v2f w2c[32];                       // w2[i][2m:2m+2] for all i
#pragma unroll
    for (int i = 0; i < 32; ++i) w2c[i] = w2v[i * 16 + m];

    // Pin the weight slices in VGPRs: opaque asm result cannot be
    // rematerialized, so the loads above stay hoisted out of the loop.
#pragma unroll
    for (int i = 0; i < 32; ++i) { asm volatile("" : "+v"(w2c[i])); }
    asm volatile("" : "+v"(w1r0), "+v"(w1r1), "+v"(w1r2), "+v"(b1c), "+v"(b2c));
    asm volatile("" : "+v"(w3r0), "+v"(w3r1));

    v2f y = ((const v2f*)x)[elem];     // ODE state (y0, y1)
    float T = fminf(samples[elem], 50.0f);
    float t = 0.0f;
    float h = 0.05f;

    // f(t, y) -> v2f, cooperative across the 16-lane group
    auto f_eval = [&](float tt, v2f z) -> v2f {
        // layer 1: own 2 columns, relu (packed)
        v2f hv = vfma(splat(tt), w1r0, vfma(splat(z.x), w1r1,
                 vfma(splat(z.y), w1r2, b1c)));
        hv = vrelu(hv);
        float hx = hv.x, hy = hv.y;

        // layer 2: 4 independent chains, gathers interleaved per 8-row block
        float g[32];
        v2f a0 = b2c, a1 = splat(0.0f), a2 = splat(0.0f), a3 = splat(0.0f);

        GPAIR(0);  GPAIR(1);  GPAIR(2);  GPAIR(3);
#pragma unroll
        for (int i = 0; i < 8; ++i)  a0 = vfma(splat(g[i]), w2c[i], a0);
        GPAIR(4);  GPAIR(5);  GPAIR(6);  GPAIR(7);
#pragma unroll
        for (int i = 8; i < 16; ++i) a1 = vfma(splat(g[i]), w2c[i], a1);
        GPAIR(8);  GPAIR(9);  GPAIR(10); GPAIR(11);
#pragma unroll
        for (int i = 16; i < 24; ++i) a2 = vfma(splat(g[i]), w2c[i], a2);
        GPAIR(12); GPAIR(13); GPAIR(14); GPAIR(15);
#pragma unroll
        for (int i = 24; i < 32; ++i) a3 = vfma(splat(g[i]), w2c[i], a3);

        v2f acc = vrelu((a0 + a1) + (a2 + a3));

        // layer 3: own 2 rows -> 2 packed FMAs, then 4-stage butterfly
        v2f p = vfma(splat(acc.x), w3r0, splat(acc.y) * w3r1);
        p = redstage<1>(p);
        p = redstage<2>(p);
        p = redstage<4>(p);
        p = redstage<8>(p);
        return p + b3c;
    };

    // FSAL: k1 for the first step; thereafter k1 = accept ? k7 : k1.
    v2f k1 = f_eval(0.0f, y);

    for (int s = 0; s < MAXS; ++s) {
        float rem = T - t;
        if (!(rem > 1e-8f)) break;              // state frozen from here on
        float hs = fminf(h, rem);
        v2f hb = splat(hs);

        v2f k2 = f_eval(t + hs * 0.2f, vfma(hb, splat(0.2f) * k1, y));
        v2f k3 = f_eval(t + hs * 0.3f,
                 vfma(hb, vfma(splat((float)(3.0/40.0)), k1, splat((float)(9.0/40.0)) * k2), y));
        v2f k4 = f_eval(t + hs * 0.8f,
                 vfma(hb, vfma(splat((float)(44.0/45.0)), k1,
                          vfma(splat((float)(-56.0/15.0)), k2, splat((float)(32.0/9.0)) * k3)), y));
        v2f k5 = f_eval(t + hs * (float)(8.0/9.0),
                 vfma(hb, vfma(splat((float)(19372.0/6561.0)), k1,
                          vfma(splat((float)(-25360.0/2187.0)), k2,
                          vfma(splat((float)(64448.0/6561.0)), k3,
                               splat((float)(-212.0/729.0)) * k4))), y));
        v2f k6 = f_eval(t + hs,
                 vfma(hb, vfma(splat((float)(9017.0/3168.0)), k1,
                          vfma(splat((float)(-355.0/33.0)), k2,
                          vfma(splat((float)(46732.0/5247.0)), k3,
                          vfma(splat((float)(49.0/176.0)), k4,
                               splat((float)(-5103.0/18656.0)) * k5)))), y));
        v2f y5 = vfma(hb, vfma(splat((float)(35.0/384.0)), k1,
                          vfma(splat((float)(500.0/1113.0)), k3,
                          vfma(splat((float)(125.0/192.0)), k4,
                          vfma(splat((float)(-2187.0/6784.0)), k5,
                               splat((float)(11.0/84.0)) * k6)))), y);
        v2f k7 = f_eval(t + hs, y5);

        v2f err = hb * vfma(splat((float)(71.0/57600.0)), k1,
                       vfma(splat((float)(-71.0/16695.0)), k3,
                       vfma(splat((float)(71.0/1920.0)), k4,
                       vfma(splat((float)(-17253.0/339200.0)), k5,
                       vfma(splat((float)(22.0/525.0)), k6,
                            splat((float)(-1.0/40.0)) * k7)))));

        v2f ay  = __builtin_elementwise_abs(y);
        v2f ay5 = __builtin_elementwise_abs(y5);
        v2f sc  = vfma(splat(0.01f), __builtin_elementwise_max(ay, ay5), splat(0.01f));
        v2f r   = err / sc;
        float en = sqrtf(0.5f * (r.x * r.x + r.y * r.y));

        float fac = 0.9f * powf(fmaxf(en, 1e-10f), -0.2f);
        fac = fminf(fmaxf(fac, 0.2f), 10.0f);

        bool accept = (en <= 1.0f);
        if (accept) { t += hs; y = y5; }
        k1 = accept ? k7 : k1;                  // FSAL (exact)
        h = hs * fac;
    }

    // final head: y @ fc_w (2x10) + fc_b; all 16 lanes hold identical y.
    if (m < 10) {
        out[10 * elem + m] = fmaf(y.x, fcw[m], fmaf(y.y, fcw[10 + m], fcb[m]));
    }
}

extern "C" void kernel_launch(void* const* d_in, const int* in_sizes, int n_in,
                              void* d_out, int out_size, void* d_ws, size_t ws_size,
                              hipStream_t stream) {
    const float* x   = (const float*)d_in[0];
    const float* sm  = (const float*)d_in[1];
    const float* w1  = (const float*)d_in[2];
    const float* b1  = (const float*)d_in[3];
    const float* w2  = (const float*)d_in[4];
    const float* b2  = (const float*)d_in[5];
    const float* w3  = (const float*)d_in[6];
    const float* b3  = (const float*)d_in[7];
    const float* fcw = (const float*)d_in[8];
    const float* fcb = (const float*)d_in[9];
    // d_in[10..15] = enc_* : dead code in the reference, unused.
    float* out = (float*)d_out;

    int n = in_sizes[1];                       // B
    const int block = 256;
    long long threads = (long long)n * 16;     // 16 lanes per element
    int grid = (int)((threads + block - 1) / block);
    node_kernel<<<grid, block, 0, stream>>>(x, sm, w1, b1, w2, b2, w3, b3,
                                            fcw, fcb, out, n);
}

// Round 5
// 105.574 us; speedup vs baseline: 1.6471x; 1.0443x over previous
//
#include <hip/hip_runtime.h>
#include <math.h>

// Neural-ODE RK45, 16 lanes per batch element — round 5.
// Bottleneck model (round-4 evidence): the LDS/DS pipe is per-CU and was
// eating 40 ds_swizzle per f_eval (32 gather + 8 butterfly) = ~16 us of
// pure DS occupancy at 16 waves/CU. This round cuts DS ops/eval 40 -> 9:
//  (1) gather: each lane ds_write_b64's its h1 pair into a 144B-padded
//      group slot, then all 16 lanes read the 32-float vector back with
//      8x ds_read_b128 at identical addresses (LDS broadcast). The 144B
//      slot stride de-conflicts the 4 groups of a wave on the b128 reads.
//  (2) layer-3 16-lane all-reduce moved to the VALU pipe via DPP
//      (v_mov_b32_dpp + v_add): stages quad_perm[1,0,3,2]=0xB1,
//      quad_perm[2,3,0,1]=0x4E, row_half_mirror=0x141, row_mirror=0x140.
//      All involutions -> every lane ends with the full sum (group-uniform
//      state preserved bitwise).
// Everything else (FSAL, packed v2f math, pinned w2 slice) unchanged.

#define MAXS 96

typedef float v2f __attribute__((ext_vector_type(2)));

static __device__ __forceinline__ v2f splat(float s) { v2f v; v.x = s; v.y = s; return v; }
static __device__ __forceinline__ v2f vfma(v2f a, v2f b, v2f c) { return __builtin_elementwise_fma(a, b, c); }
static __device__ __forceinline__ v2f vrelu(v2f a) { return __builtin_elementwise_max(a, splat(0.0f)); }

template<int CTRL>
static __device__ __forceinline__ float dppf(float x) {
    return __int_as_float(__builtin_amdgcn_update_dpp(
        0, __float_as_int(x), CTRL, 0xF, 0xF, false));
}

// 16-lane all-reduce sum on the VALU pipe (DPP), all lanes get the total.
static __device__ __forceinline__ v2f dpp_allreduce16(v2f p) {
    p.x += dppf<0xB1>(p.x);  p.y += dppf<0xB1>(p.y);   // xor 1 (quad_perm)
    p.x += dppf<0x4E>(p.x);  p.y += dppf<0x4E>(p.y);   // xor 2 (quad_perm)
    p.x += dppf<0x141>(p.x); p.y += dppf<0x141>(p.y);  // row_half_mirror
    p.x += dppf<0x140>(p.x); p.y += dppf<0x140>(p.y);  // row_mirror
    return p;
}

__global__ __launch_bounds__(256, 3) void node_kernel(
    const float* __restrict__ x, const float* __restrict__ samples,
    const float* __restrict__ w1, const float* __restrict__ b1,
    const float* __restrict__ w2, const float* __restrict__ b2,
    const float* __restrict__ w3, const float* __restrict__ b3,
    const float* __restrict__ fcw, const float* __restrict__ fcb,
    float* __restrict__ out, int n)
{
    const int tid  = blockIdx.x * blockDim.x + threadIdx.x;
    const int elem = tid >> 4;
    const int m    = tid & 15;
    if (elem >= n) return;

    // 16 groups/block, 36 floats (144 B) per group: 8B-write and 16B-read
    // aligned, and the stride staggers the 4 groups of a wave across banks.
    __shared__ float lds[16 * 36];
    float* slot = &lds[(threadIdx.x >> 4) * 36];

    // ---- preload this lane's weight slices (once) ----
    const v2f* w1v = (const v2f*)w1;   // (3,32) row-major -> 16 pairs/row
    const v2f* b1v = (const v2f*)b1;
    const v2f* w2v = (const v2f*)w2;   // (32,32) row-major
    const v2f* b2v = (const v2f*)b2;
    const v2f* w3v = (const v2f*)w3;   // (32,2) row-major -> row r = w3v[r]

    v2f w1r0 = w1v[0 * 16 + m];        // w1[0][2m:2m+2]
    v2f w1r1 = w1v[1 * 16 + m];
    v2f w1r2 = w1v[2 * 16 + m];
    v2f b1c  = b1v[m];
    v2f b2c  = b2v[m];
    v2f w3r0 = w3v[2 * m + 0];         // full row 2m   of w3
    v2f w3r1 = w3v[2 * m + 1];         // full row 2m+1
    v2f b3c  = { b3[0], b3[1] };

    v2f w2c[32];                       // w2[i][2m:2m+2] for all i
#pragma unroll
    for (int i = 0; i < 32; ++i) w2c[i] = w2v[i * 16 + m];

    // Pin weight slices in VGPRs (prevents remat into the loop).
#pragma unroll
    for (int i = 0; i < 32; ++i) { asm volatile("" : "+v"(w2c[i])); }
    asm volatile("" : "+v"(w1r0), "+v"(w1r1), "+v"(w1r2), "+v"(b1c), "+v"(b2c));
    asm volatile("" : "+v"(w3r0), "+v"(w3r1));

    v2f y = ((const v2f*)x)[elem];     // ODE state (y0, y1)
    float T = fminf(samples[elem], 50.0f);
    float t = 0.0f;
    float h = 0.05f;

    // f(t, y) -> v2f, cooperative across the 16-lane group
    auto f_eval = [&](float tt, v2f z) -> v2f {
        // layer 1: own 2 columns, relu (packed)
        v2f hv = vfma(splat(tt), w1r0, vfma(splat(z.x), w1r1,
                 vfma(splat(z.y), w1r2, b1c)));
        hv = vrelu(hv);

        // publish own h1 pair; same-wave DS ops stay ordered, no barrier
        ((v2f*)slot)[m] = hv;

        // broadcast-read the full 32-wide h1 (8x ds_read_b128)
        const float4* gp = (const float4*)slot;
        float4 r0 = gp[0], r1 = gp[1], r2 = gp[2], r3 = gp[3];
        float4 r4 = gp[4], r5 = gp[5], r6 = gp[6], r7 = gp[7];

        // layer 2: 4 independent packed accumulator chains
        v2f a0 = b2c, a1 = splat(0.0f), a2 = splat(0.0f), a3 = splat(0.0f);
        a0 = vfma(splat(r0.x), w2c[ 0], a0); a1 = vfma(splat(r0.y), w2c[ 1], a1);
        a2 = vfma(splat(r0.z), w2c[ 2], a2); a3 = vfma(splat(r0.w), w2c[ 3], a3);
        a0 = vfma(splat(r1.x), w2c[ 4], a0); a1 = vfma(splat(r1.y), w2c[ 5], a1);
        a2 = vfma(splat(r1.z), w2c[ 6], a2); a3 = vfma(splat(r1.w), w2c[ 7], a3);
        a0 = vfma(splat(r2.x), w2c[ 8], a0); a1 = vfma(splat(r2.y), w2c[ 9], a1);
        a2 = vfma(splat(r2.z), w2c[10], a2); a3 = vfma(splat(r2.w), w2c[11], a3);
        a0 = vfma(splat(r3.x), w2c[12], a0); a1 = vfma(splat(r3.y), w2c[13], a1);
        a2 = vfma(splat(r3.z), w2c[14], a2); a3 = vfma(splat(r3.w), w2c[15], a3);
        a0 = vfma(splat(r4.x), w2c[16], a0); a1 = vfma(splat(r4.y), w2c[17], a1);
        a2 = vfma(splat(r4.z), w2c[18], a2); a3 = vfma(splat(r4.w), w2c[19], a3);
        a0 = vfma(splat(r5.x), w2c[20], a0); a1 = vfma(splat(r5.y), w2c[21], a1);
        a2 = vfma(splat(r5.z), w2c[22], a2); a3 = vfma(splat(r5.w), w2c[23], a3);
        a0 = vfma(splat(r6.x), w2c[24], a0); a1 = vfma(splat(r6.y), w2c[25], a1);
        a2 = vfma(splat(r6.z), w2c[26], a2); a3 = vfma(splat(r6.w), w2c[27], a3);
        a0 = vfma(splat(r7.x), w2c[28], a0); a1 = vfma(splat(r7.y), w2c[29], a1);
        a2 = vfma(splat(r7.z), w2c[30], a2); a3 = vfma(splat(r7.w), w2c[31], a3);

        v2f acc = vrelu((a0 + a1) + (a2 + a3));

        // layer 3: own 2 rows -> 2 packed FMAs, then DPP all-reduce (VALU)
        v2f p = vfma(splat(acc.x), w3r0, splat(acc.y) * w3r1);
        p = dpp_allreduce16(p);
        return p + b3c;
    };

    // FSAL: k1 for the first step; thereafter k1 = accept ? k7 : k1.
    v2f k1 = f_eval(0.0f, y);

    for (int s = 0; s < MAXS; ++s) {
        float rem = T - t;
        if (!(rem > 1e-8f)) break;              // state frozen from here on
        float hs = fminf(h, rem);
        v2f hb = splat(hs);

        v2f k2 = f_eval(t + hs * 0.2f, vfma(hb, splat(0.2f) * k1, y));
        v2f k3 = f_eval(t + hs * 0.3f,
                 vfma(hb, vfma(splat((float)(3.0/40.0)), k1, splat((float)(9.0/40.0)) * k2), y));
        v2f k4 = f_eval(t + hs * 0.8f,
                 vfma(hb, vfma(splat((float)(44.0/45.0)), k1,
                          vfma(splat((float)(-56.0/15.0)), k2, splat((float)(32.0/9.0)) * k3)), y));
        v2f k5 = f_eval(t + hs * (float)(8.0/9.0),
                 vfma(hb, vfma(splat((float)(19372.0/6561.0)), k1,
                          vfma(splat((float)(-25360.0/2187.0)), k2,
                          vfma(splat((float)(64448.0/6561.0)), k3,
                               splat((float)(-212.0/729.0)) * k4))), y));
        v2f k6 = f_eval(t + hs,
                 vfma(hb, vfma(splat((float)(9017.0/3168.0)), k1,
                          vfma(splat((float)(-355.0/33.0)), k2,
                          vfma(splat((float)(46732.0/5247.0)), k3,
                          vfma(splat((float)(49.0/176.0)), k4,
                               splat((float)(-5103.0/18656.0)) * k5)))), y));
        v2f y5 = vfma(hb, vfma(splat((float)(35.0/384.0)), k1,
                          vfma(splat((float)(500.0/1113.0)), k3,
                          vfma(splat((float)(125.0/192.0)), k4,
                          vfma(splat((float)(-2187.0/6784.0)), k5,
                               splat((float)(11.0/84.0)) * k6)))), y);
        v2f k7 = f_eval(t + hs, y5);

        v2f err = hb * vfma(splat((float)(71.0/57600.0)), k1,
                       vfma(splat((float)(-71.0/16695.0)), k3,
                       vfma(splat((float)(71.0/1920.0)), k4,
                       vfma(splat((float)(-17253.0/339200.0)), k5,
                       vfma(splat((float)(22.0/525.0)), k6,
                            splat((float)(-1.0/40.0)) * k7)))));

        v2f ay  = __builtin_elementwise_abs(y);
        v2f ay5 = __builtin_elementwise_abs(y5);
        v2f sc  = vfma(splat(0.01f), __builtin_elementwise_max(ay, ay5), splat(0.01f));
        v2f r   = err / sc;
        float en = sqrtf(0.5f * (r.x * r.x + r.y * r.y));

        float fac = 0.9f * powf(fmaxf(en, 1e-10f), -0.2f);
        fac = fminf(fmaxf(fac, 0.2f), 10.0f);

        bool accept = (en <= 1.0f);
        if (accept) { t += hs; y = y5; }
        k1 = accept ? k7 : k1;                  // FSAL (exact)
        h = hs * fac;
    }

    // final head: y @ fc_w (2x10) + fc_b; all 16 lanes hold identical y.
    if (m < 10) {
        out[10 * elem + m] = fmaf(y.x, fcw[m], fmaf(y.y, fcw[10 + m], fcb[m]));
    }
}

extern "C" void kernel_launch(void* const* d_in, const int* in_sizes, int n_in,
                              void* d_out, int out_size, void* d_ws, size_t ws_size,
                              hipStream_t stream) {
    const float* x   = (const float*)d_in[0];
    const float* sm  = (const float*)d_in[1];
    const float* w1  = (const float*)d_in[2];
    const float* b1  = (const float*)d_in[3];
    const float* w2  = (const float*)d_in[4];
    const float* b2  = (const float*)d_in[5];
    const float* w3  = (const float*)d_in[6];
    const float* b3  = (const float*)d_in[7];
    const float* fcw = (const float*)d_in[8];
    const float* fcb = (const float*)d_in[9];
    // d_in[10..15] = enc_* : dead code in the reference, unused.
    float* out = (float*)d_out;

    int n = in_sizes[1];                       // B
    const int block = 256;
    long long threads = (long long)n * 16;     // 16 lanes per element
    int grid = (int)((threads + block - 1) / block);
    node_kernel<<<grid, block, 0, stream>>>(x, sm, w1, b1, w2, b2, w3, b3,
                                            fcw, fcb, out, n);
}

// Round 6
// 105.166 us; speedup vs baseline: 1.6535x; 1.0039x over previous
//
#include <hip/hip_runtime.h>
#include <math.h>

// Neural-ODE RK45 — round 6: 16 lanes per GROUP, 2 elements per group.
// The two elements ride the two halves of every packed-fp32 instruction
// (v_pk_fma_f32): layer-1/layer-3/RK-glue instruction counts halve per
// element; layer-2 uses op_sel broadcast (splat-lo/hi of the same 64-VGPR
// w2 slice) so its count is unchanged. 16384 elems / 8 per wave = 2048
// waves = exactly 2 resident waves per SIMD on all 1024 SIMDs (no tail
// rounds). __launch_bounds__(256,2) -> 256-VGPR budget, no spill risk.
// Gather: 1x ds_write_b128 + 16x broadcast ds_read_b128 per eval-pair;
// 16-lane all-reduce on the VALU pipe via DPP mirrors. FSAL kept.

#define MAXS 96

typedef float v2f __attribute__((ext_vector_type(2)));

static __device__ __forceinline__ v2f splat(float s){ v2f v; v.x=s; v.y=s; return v; }
static __device__ __forceinline__ v2f vfma(v2f a, v2f b, v2f c){ return __builtin_elementwise_fma(a,b,c); }
static __device__ __forceinline__ v2f vrelu(v2f a){ return __builtin_elementwise_max(a, splat(0.0f)); }
static __device__ __forceinline__ v2f slo(v2f v){ return __builtin_shufflevector(v,v,0,0); }
static __device__ __forceinline__ v2f shi(v2f v){ return __builtin_shufflevector(v,v,1,1); }

template<int CTRL>
static __device__ __forceinline__ float dppf(float x){
    return __int_as_float(__builtin_amdgcn_update_dpp(0, __float_as_int(x), CTRL, 0xF, 0xF, false));
}
// 16-lane all-reduce sum (VALU pipe); involutive stages -> bitwise
// group-uniform result on every lane.
static __device__ __forceinline__ v2f dpp_allreduce16(v2f p){
    p.x += dppf<0xB1>(p.x);  p.y += dppf<0xB1>(p.y);   // quad_perm xor1
    p.x += dppf<0x4E>(p.x);  p.y += dppf<0x4E>(p.y);   // quad_perm xor2
    p.x += dppf<0x141>(p.x); p.y += dppf<0x141>(p.y);  // row_half_mirror
    p.x += dppf<0x140>(p.x); p.y += dppf<0x140>(p.y);  // row_mirror
    return p;
}

__global__ __launch_bounds__(256, 2) void node_kernel(
    const float* __restrict__ x, const float* __restrict__ samples,
    const float* __restrict__ w1, const float* __restrict__ b1,
    const float* __restrict__ w2, const float* __restrict__ b2,
    const float* __restrict__ w3, const float* __restrict__ b3,
    const float* __restrict__ fcw, const float* __restrict__ fcb,
    float* __restrict__ out, int n)
{
    const int tid = blockIdx.x * blockDim.x + threadIdx.x;
    const int gid = tid >> 4;            // group: elements 2*gid, 2*gid+1
    const int m   = tid & 15;
    const int eA  = 2 * gid, eB = 2 * gid + 1;
    if (eA >= n) return;
    const bool hasB = (eB < n);

    // 16 groups/block, 68-float (272 B) slots: 16B-aligned, 4-bank stagger
    // between the 4 groups of a wave on the broadcast b128 reads.
    __shared__ float lds[16 * 68];
    float* slot = &lds[(threadIdx.x >> 4) * 68];

    // ---- weight slices (lane m owns hidden columns 2m, 2m+1) ----
    const v2f* w2v = (const v2f*)w2;     // (32,32) row-major
    v2f w2c[32];                         // w2[j][2m:2m+2] for all j
#pragma unroll
    for (int j = 0; j < 32; ++j) w2c[j] = w2v[j * 16 + m];

    v2f w1s00 = splat(w1[ 0 + 2*m]), w1s01 = splat(w1[ 0 + 2*m + 1]);
    v2f w1s10 = splat(w1[32 + 2*m]), w1s11 = splat(w1[32 + 2*m + 1]);
    v2f w1s20 = splat(w1[64 + 2*m]), w1s21 = splat(w1[64 + 2*m + 1]);
    v2f b1s0  = splat(b1[2*m]),      b1s1  = splat(b1[2*m + 1]);
    v2f b2s0  = splat(b2[2*m]),      b2s1  = splat(b2[2*m + 1]);
    v2f w3s00 = splat(w3[(2*m)*2+0]),   w3s01 = splat(w3[(2*m)*2+1]);
    v2f w3s10 = splat(w3[(2*m+1)*2+0]), w3s11 = splat(w3[(2*m+1)*2+1]);
    v2f b3s0  = splat(b3[0]),        b3s1  = splat(b3[1]);

    // Pin in VGPRs (prevents in-loop rematerialization; round-3 evidence).
#pragma unroll
    for (int j = 0; j < 32; ++j) { asm volatile("" : "+v"(w2c[j])); }
    asm volatile("" : "+v"(w1s00), "+v"(w1s01), "+v"(w1s10), "+v"(w1s11));
    asm volatile("" : "+v"(w1s20), "+v"(w1s21), "+v"(b1s0), "+v"(b1s1));
    asm volatile("" : "+v"(b2s0), "+v"(b2s1));
    asm volatile("" : "+v"(w3s00), "+v"(w3s01), "+v"(w3s10), "+v"(w3s11));

    // ---- ODE state, elements A/B in pk halves ----
    v2f xA = ((const v2f*)x)[eA];
    v2f xB = hasB ? ((const v2f*)x)[eB] : xA;
    v2f y0pk; y0pk.x = xA.x; y0pk.y = xB.x;
    v2f y1pk; y1pk.x = xA.y; y1pk.y = xB.y;
    float TA = fminf(samples[eA], 50.0f);
    float TB = hasB ? fminf(samples[eB], 50.0f) : TA;
    v2f tpk = splat(0.0f);
    v2f hpk = splat(0.05f);

    // f(t, y) for both elements at once
    auto f_eval = [&](v2f tt, v2f z0, v2f z1, v2f& o0, v2f& o1) {
        // layer 1: own 2 columns, both elements packed
        v2f hc0 = vrelu(vfma(tt, w1s00, vfma(z0, w1s10, vfma(z1, w1s20, b1s0))));
        v2f hc1 = vrelu(vfma(tt, w1s01, vfma(z0, w1s11, vfma(z1, w1s21, b1s1))));
        // publish (A[2m],B[2m],A[2m+1],B[2m+1]); same-wave DS is ordered
        float4 wv; wv.x = hc0.x; wv.y = hc0.y; wv.z = hc1.x; wv.w = hc1.y;
        ((float4*)slot)[m] = wv;
        // broadcast-read all 32 (A,B) pairs; 4 chains x 16 deep
        const float4* gp = (const float4*)slot;
        v2f a0 = b2s0, a1 = splat(0.0f), a2 = b2s1, a3 = splat(0.0f);
#pragma unroll
        for (int j = 0; j < 16; ++j) {
            float4 r = gp[j];
            v2f pA; pA.x = r.x; pA.y = r.y;      // h1 pair, col 2j
            v2f pB; pB.x = r.z; pB.y = r.w;      // h1 pair, col 2j+1
            a0 = vfma(pA, slo(w2c[2*j]),     a0);
            a2 = vfma(pA, shi(w2c[2*j]),     a2);
            a1 = vfma(pB, slo(w2c[2*j + 1]), a1);
            a3 = vfma(pB, shi(w2c[2*j + 1]), a3);
        }
        v2f h20 = vrelu(a0 + a1);                // own col 2m
        v2f h21 = vrelu(a2 + a3);                // own col 2m+1
        // layer 3 partial + DPP all-reduce (VALU pipe)
        v2f p0 = vfma(h20, w3s00, h21 * w3s10);
        v2f p1 = vfma(h20, w3s01, h21 * w3s11);
        p0 = dpp_allreduce16(p0);
        p1 = dpp_allreduce16(p1);
        o0 = p0 + b3s0;
        o1 = p1 + b3s1;
    };

    // FSAL: initial k1; thereafter k1 = accept ? k7 : k1 (per half, exact).
    v2f k10, k11; f_eval(tpk, y0pk, y1pk, k10, k11);

    for (int s = 0; s < MAXS; ++s) {
        float remA = TA - tpk.x, remB = TB - tpk.y;
        bool actA = remA > 1e-8f;
        bool actB = hasB && (remB > 1e-8f);
        if (!actA && !actB) break;
        float hsA = actA ? fminf(hpk.x, remA) : 0.0f;
        float hsB = actB ? fminf(hpk.y, remB) : 0.0f;
        v2f hb; hb.x = hsA; hb.y = hsB;

        v2f k20,k21,k30,k31,k40,k41,k50,k51,k60,k61,k70,k71,u0,u1,y50,y51;

        u0 = vfma(hb, splat(0.2f) * k10, y0pk);
        u1 = vfma(hb, splat(0.2f) * k11, y1pk);
        f_eval(tpk + hb * splat(0.2f), u0, u1, k20, k21);

        u0 = vfma(hb, vfma(splat((float)(3.0/40.0)), k10, splat((float)(9.0/40.0)) * k20), y0pk);
        u1 = vfma(hb, vfma(splat((float)(3.0/40.0)), k11, splat((float)(9.0/40.0)) * k21), y1pk);
        f_eval(tpk + hb * splat(0.3f), u0, u1, k30, k31);

        u0 = vfma(hb, vfma(splat((float)(44.0/45.0)), k10,
                  vfma(splat((float)(-56.0/15.0)), k20, splat((float)(32.0/9.0)) * k30)), y0pk);
        u1 = vfma(hb, vfma(splat((float)(44.0/45.0)), k11,
                  vfma(splat((float)(-56.0/15.0)), k21, splat((float)(32.0/9.0)) * k31)), y1pk);
        f_eval(tpk + hb * splat(0.8f), u0, u1, k40, k41);

        u0 = vfma(hb, vfma(splat((float)(19372.0/6561.0)), k10,
                  vfma(splat((float)(-25360.0/2187.0)), k20,
                  vfma(splat((float)(64448.0/6561.0)), k30,
                       splat((float)(-212.0/729.0)) * k40))), y0pk);
        u1 = vfma(hb, vfma(splat((float)(19372.0/6561.0)), k11,
                  vfma(splat((float)(-25360.0/2187.0)), k21,
                  vfma(splat((float)(64448.0/6561.0)), k31,
                       splat((float)(-212.0/729.0)) * k41))), y1pk);
        f_eval(tpk + hb * splat((float)(8.0/9.0)), u0, u1, k50, k51);

        u0 = vfma(hb, vfma(splat((float)(9017.0/3168.0)), k10,
                  vfma(splat((float)(-355.0/33.0)), k20,
                  vfma(splat((float)(46732.0/5247.0)), k30,
                  vfma(splat((float)(49.0/176.0)), k40,
                       splat((float)(-5103.0/18656.0)) * k50)))), y0pk);
        u1 = vfma(hb, vfma(splat((float)(9017.0/3168.0)), k11,
                  vfma(splat((float)(-355.0/33.0)), k21,
                  vfma(splat((float)(46732.0/5247.0)), k31,
                  vfma(splat((float)(49.0/176.0)), k41,
                       splat((float)(-5103.0/18656.0)) * k51)))), y1pk);
        f_eval(tpk + hb, u0, u1, k60, k61);

        y50 = vfma(hb, vfma(splat((float)(35.0/384.0)), k10,
                   vfma(splat((float)(500.0/1113.0)), k30,
                   vfma(splat((float)(125.0/192.0)), k40,
                   vfma(splat((float)(-2187.0/6784.0)), k50,
                        splat((float)(11.0/84.0)) * k60)))), y0pk);
        y51 = vfma(hb, vfma(splat((float)(35.0/384.0)), k11,
                   vfma(splat((float)(500.0/1113.0)), k31,
                   vfma(splat((float)(125.0/192.0)), k41,
                   vfma(splat((float)(-2187.0/6784.0)), k51,
                        splat((float)(11.0/84.0)) * k61)))), y1pk);
        f_eval(tpk + hb, y50, y51, k70, k71);

        v2f err0 = hb * vfma(splat((float)(71.0/57600.0)), k10,
                        vfma(splat((float)(-71.0/16695.0)), k30,
                        vfma(splat((float)(71.0/1920.0)), k40,
                        vfma(splat((float)(-17253.0/339200.0)), k50,
                        vfma(splat((float)(22.0/525.0)), k60,
                             splat((float)(-1.0/40.0)) * k70)))));
        v2f err1 = hb * vfma(splat((float)(71.0/57600.0)), k11,
                        vfma(splat((float)(-71.0/16695.0)), k31,
                        vfma(splat((float)(71.0/1920.0)), k41,
                        vfma(splat((float)(-17253.0/339200.0)), k51,
                        vfma(splat((float)(22.0/525.0)), k61,
                             splat((float)(-1.0/40.0)) * k71)))));

        v2f sc0 = vfma(splat(0.01f),
                  __builtin_elementwise_max(__builtin_elementwise_abs(y0pk),
                                            __builtin_elementwise_abs(y50)), splat(0.01f));
        v2f sc1 = vfma(splat(0.01f),
                  __builtin_elementwise_max(__builtin_elementwise_abs(y1pk),
                                            __builtin_elementwise_abs(y51)), splat(0.01f));
        v2f r0 = err0 / sc0;
        v2f r1 = err1 / sc1;

        float enA = sqrtf(0.5f * (r0.x * r0.x + r1.x * r1.x));
        float enB = sqrtf(0.5f * (r0.y * r0.y + r1.y * r1.y));
        float facA = fminf(fmaxf(0.9f * exp2f(-0.2f * log2f(fmaxf(enA, 1e-10f))), 0.2f), 10.0f);
        float facB = fminf(fmaxf(0.9f * exp2f(-0.2f * log2f(fmaxf(enB, 1e-10f))), 0.2f), 10.0f);

        bool accA = actA && (enA <= 1.0f);
        bool accB = actB && (enB <= 1.0f);
        if (accA) { tpk.x += hsA; y0pk.x = y50.x; y1pk.x = y51.x; k10.x = k70.x; k11.x = k71.x; }
        if (accB) { tpk.y += hsB; y0pk.y = y50.y; y1pk.y = y51.y; k10.y = k70.y; k11.y = k71.y; }
        if (actA) hpk.x = hsA * facA;
        if (actB) hpk.y = hsB * facB;
    }

    // final head: y @ fc_w (2x10) + fc_b, per element half
    if (m < 10) {
        out[10 * eA + m] = fmaf(y0pk.x, fcw[m], fmaf(y1pk.x, fcw[10 + m], fcb[m]));
        if (hasB)
            out[10 * eB + m] = fmaf(y0pk.y, fcw[m], fmaf(y1pk.y, fcw[10 + m], fcb[m]));
    }
}

extern "C" void kernel_launch(void* const* d_in, const int* in_sizes, int n_in,
                              void* d_out, int out_size, void* d_ws, size_t ws_size,
                              hipStream_t stream) {
    const float* x   = (const float*)d_in[0];
    const float* sm  = (const float*)d_in[1];
    const float* w1  = (const float*)d_in[2];
    const float* b1  = (const float*)d_in[3];
    const float* w2  = (const float*)d_in[4];
    const float* b2  = (const float*)d_in[5];
    const float* w3  = (const float*)d_in[6];
    const float* b3  = (const float*)d_in[7];
    const float* fcw = (const float*)d_in[8];
    const float* fcb = (const float*)d_in[9];
    // d_in[10..15] = enc_* : dead code in the reference, unused.
    float* out = (float*)d_out;

    int n = in_sizes[1];                            // B
    const int block = 256;
    long long groups  = (n + 1) / 2;                // 2 elements per group
    long long threads = groups * 16;                // 16 lanes per group
    int grid = (int)((threads + block - 1) / block);
    node_kernel<<<grid, block, 0, stream>>>(x, sm, w1, b1, w2, b2, w3, b3,
                                            fcw, fcb, out, n);
}

// Round 7
// 101.333 us; speedup vs baseline: 1.7160x; 1.0378x over previous
//
#include <hip/hip_runtime.h>
#include <math.h>

// Neural-ODE RK45 — round 7: 8 lanes per element.
// Invariant found in r2-r6: all shapes plateaued at 35-41 us because the
// per-CU LDS pipe was saturated (every lane re-read the whole gathered h1:
// 272 B/lane/eval in r6 -> ~23 us of mandatory DS occupancy at 8 waves/CU).
// This round: lane m (=tid&7) owns hidden cols [4m,4m+4) (w2 slice = 128
// VGPRs, pinned). Intra-QUAD exchange of h1 uses quad_perm DPP broadcasts
// (VALU pipe, zero DS); only the other quad's 16 floats cross LDS:
// 1x ds_write_b128 + 4x broadcast ds_read_b128 = 80 B/lane/eval (3.4x less
// DS than r6). 131072 threads = 2048 waves = 2 resident waves/SIMD.
// Slot stride 144 B -> <=2-way bank aliasing on the b128 reads (free).
// FSAL + v2f(state)-packed RK glue + exp2/log2 step controller kept.

#define MAXS 96

typedef float v2f __attribute__((ext_vector_type(2)));

static __device__ __forceinline__ v2f splat(float s){ v2f v; v.x=s; v.y=s; return v; }
static __device__ __forceinline__ v2f vfma(v2f a, v2f b, v2f c){ return __builtin_elementwise_fma(a,b,c); }
static __device__ __forceinline__ v2f vrelu(v2f a){ return __builtin_elementwise_max(a, splat(0.0f)); }

template<int CTRL>
static __device__ __forceinline__ float dppf(float x){
    return __int_as_float(__builtin_amdgcn_update_dpp(0, __float_as_int(x), CTRL, 0xF, 0xF, false));
}
// quad_perm broadcast of lane s (within each 4-lane quad): ctrl = s*0x55
// 8-lane all-reduce: xor1 (0xB1), xor2 (0x4E), 8-lane mirror (0x141)
static __device__ __forceinline__ v2f dpp_allreduce8(v2f p){
    p.x += dppf<0xB1>(p.x);  p.y += dppf<0xB1>(p.y);
    p.x += dppf<0x4E>(p.x);  p.y += dppf<0x4E>(p.y);
    p.x += dppf<0x141>(p.x); p.y += dppf<0x141>(p.y);
    return p;
}

__global__ __launch_bounds__(256, 2) void node_kernel(
    const float* __restrict__ x, const float* __restrict__ samples,
    const float* __restrict__ w1, const float* __restrict__ b1,
    const float* __restrict__ w2, const float* __restrict__ b2,
    const float* __restrict__ w3, const float* __restrict__ b3,
    const float* __restrict__ fcw, const float* __restrict__ fcb,
    float* __restrict__ out, int n)
{
    const int tid  = blockIdx.x * blockDim.x + threadIdx.x;
    const int elem = tid >> 3;
    const int m    = tid & 7;            // lane in 8-lane group
    if (elem >= n) return;
    const int q = m >> 2;                // quad within group (0 or 1)

    // 32 groups/block, 36-float (144 B) slots: 16B-aligned, groups stagger
    // by 4 banks -> <=2-way aliasing on the broadcast b128 reads.
    __shared__ float lds[32 * 36];
    float* slot = &lds[(threadIdx.x >> 3) * 36];
    const int mineBase  = 16 * q;        // my quad's 16 cols
    const int otherBase = 16 - mineBase; // the other quad's 16 cols

    // ---- weight slices: lane owns cols [4m,4m+4) ----
    const float4* w2v4 = (const float4*)w2;   // (32,32): row i, col-quad m
    v2f w2mA[16], w2mB[16];   // rows mineBase+k  -> own col pair A={4m,4m+1}, B={4m+2,4m+3}
    v2f w2oA[16], w2oB[16];   // rows otherBase+k
#pragma unroll
    for (int k = 0; k < 16; ++k) {
        float4 rm = w2v4[(mineBase  + k) * 8 + m];
        float4 ro = w2v4[(otherBase + k) * 8 + m];
        w2mA[k].x = rm.x; w2mA[k].y = rm.y; w2mB[k].x = rm.z; w2mB[k].y = rm.w;
        w2oA[k].x = ro.x; w2oA[k].y = ro.y; w2oB[k].x = ro.z; w2oB[k].y = ro.w;
    }
    float4 w1f0 = ((const float4*)w1)[0 * 8 + m];   // w1[0][4m..4m+4)
    float4 w1f1 = ((const float4*)w1)[1 * 8 + m];
    float4 w1f2 = ((const float4*)w1)[2 * 8 + m];
    float4 b1f  = ((const float4*)b1)[m];
    float4 b2f  = ((const float4*)b2)[m];
    v2f w1_0A = {w1f0.x, w1f0.y}, w1_0B = {w1f0.z, w1f0.w};
    v2f w1_1A = {w1f1.x, w1f1.y}, w1_1B = {w1f1.z, w1f1.w};
    v2f w1_2A = {w1f2.x, w1f2.y}, w1_2B = {w1f2.z, w1f2.w};
    v2f b1A   = {b1f.x,  b1f.y }, b1B   = {b1f.z,  b1f.w };
    v2f b2A   = {b2f.x,  b2f.y }, b2B   = {b2f.z,  b2f.w };
    const v2f* w3v = (const v2f*)w3;               // row r = (w3[r][0], w3[r][1])
    v2f w3r0 = w3v[4*m+0], w3r1 = w3v[4*m+1], w3r2 = w3v[4*m+2], w3r3 = w3v[4*m+3];
    v2f b3c  = { b3[0], b3[1] };

    // Pin in VGPRs (round-3 evidence: prevents in-loop rematerialization).
#pragma unroll
    for (int k = 0; k < 16; ++k) {
        asm volatile("" : "+v"(w2mA[k]), "+v"(w2mB[k]), "+v"(w2oA[k]), "+v"(w2oB[k]));
    }
    asm volatile("" : "+v"(w1_0A), "+v"(w1_0B), "+v"(w1_1A), "+v"(w1_1B));
    asm volatile("" : "+v"(w1_2A), "+v"(w1_2B), "+v"(b1A), "+v"(b1B));
    asm volatile("" : "+v"(b2A), "+v"(b2B));
    asm volatile("" : "+v"(w3r0), "+v"(w3r1), "+v"(w3r2), "+v"(w3r3));

    v2f y = ((const v2f*)x)[elem];       // ODE state (y0, y1)
    float T = fminf(samples[elem], 50.0f);
    float t = 0.0f;
    float h = 0.05f;

    // f(t, y) -> v2f, cooperative across the 8-lane group
    auto f_eval = [&](float tt, v2f z) -> v2f {
        // layer 1: own 4 cols (2 packed pairs), relu
        v2f hA = vrelu(vfma(splat(tt), w1_0A, vfma(splat(z.x), w1_1A, vfma(splat(z.y), w1_2A, b1A))));
        v2f hB = vrelu(vfma(splat(tt), w1_0B, vfma(splat(z.x), w1_1B, vfma(splat(z.y), w1_2B, b1B))));

        // publish own 4 cols to LDS (for the other quad); same-wave DS is ordered
        float4 wv; wv.x = hA.x; wv.y = hA.y; wv.z = hB.x; wv.w = hB.y;
        ((float4*)slot)[m] = wv;

        // own-quad 16 cols via quad_perm DPP broadcasts (VALU pipe)
        float mg0  = dppf<0x00>(hA.x), mg1  = dppf<0x00>(hA.y),
              mg2  = dppf<0x00>(hB.x), mg3  = dppf<0x00>(hB.y);
        float mg4  = dppf<0x55>(hA.x), mg5  = dppf<0x55>(hA.y),
              mg6  = dppf<0x55>(hB.x), mg7  = dppf<0x55>(hB.y);
        float mg8  = dppf<0xAA>(hA.x), mg9  = dppf<0xAA>(hA.y),
              mg10 = dppf<0xAA>(hB.x), mg11 = dppf<0xAA>(hB.y);
        float mg12 = dppf<0xFF>(hA.x), mg13 = dppf<0xFF>(hA.y),
              mg14 = dppf<0xFF>(hB.x), mg15 = dppf<0xFF>(hB.y);

        // other-quad 16 cols: 4 broadcast b128 reads
        const float4* op = (const float4*)(slot + otherBase);
        float4 o0 = op[0], o1 = op[1], o2 = op[2], o3 = op[3];

        // layer 2: 4 independent packed chains (mine->aA/aB, other->cA/cB)
        v2f aA = b2A, aB = b2B, cA = splat(0.0f), cB = splat(0.0f);
        aA = vfma(splat(mg0 ), w2mA[ 0], aA); aB = vfma(splat(mg0 ), w2mB[ 0], aB);
        aA = vfma(splat(mg1 ), w2mA[ 1], aA); aB = vfma(splat(mg1 ), w2mB[ 1], aB);
        aA = vfma(splat(mg2 ), w2mA[ 2], aA); aB = vfma(splat(mg2 ), w2mB[ 2], aB);
        aA = vfma(splat(mg3 ), w2mA[ 3], aA); aB = vfma(splat(mg3 ), w2mB[ 3], aB);
        aA = vfma(splat(mg4 ), w2mA[ 4], aA); aB = vfma(splat(mg4 ), w2mB[ 4], aB);
        aA = vfma(splat(mg5 ), w2mA[ 5], aA); aB = vfma(splat(mg5 ), w2mB[ 5], aB);
        aA = vfma(splat(mg6 ), w2mA[ 6], aA); aB = vfma(splat(mg6 ), w2mB[ 6], aB);
        aA = vfma(splat(mg7 ), w2mA[ 7], aA); aB = vfma(splat(mg7 ), w2mB[ 7], aB);
        aA = vfma(splat(mg8 ), w2mA[ 8], aA); aB = vfma(splat(mg8 ), w2mB[ 8], aB);
        aA = vfma(splat(mg9 ), w2mA[ 9], aA); aB = vfma(splat(mg9 ), w2mB[ 9], aB);
        aA = vfma(splat(mg10), w2mA[10], aA); aB = vfma(splat(mg10), w2mB[10], aB);
        aA = vfma(splat(mg11), w2mA[11], aA); aB = vfma(splat(mg11), w2mB[11], aB);
        aA = vfma(splat(mg12), w2mA[12], aA); aB = vfma(splat(mg12), w2mB[12], aB);
        aA = vfma(splat(mg13), w2mA[13], aA); aB = vfma(splat(mg13), w2mB[13], aB);
        aA = vfma(splat(mg14), w2mA[14], aA); aB = vfma(splat(mg14), w2mB[14], aB);
        aA = vfma(splat(mg15), w2mA[15], aA); aB = vfma(splat(mg15), w2mB[15], aB);
        cA = vfma(splat(o0.x), w2oA[ 0], cA); cB = vfma(splat(o0.x), w2oB[ 0], cB);
        cA = vfma(splat(o0.y), w2oA[ 1], cA); cB = vfma(splat(o0.y), w2oB[ 1], cB);
        cA = vfma(splat(o0.z), w2oA[ 2], cA); cB = vfma(splat(o0.z), w2oB[ 2], cB);
        cA = vfma(splat(o0.w), w2oA[ 3], cA); cB = vfma(splat(o0.w), w2oB[ 3], cB);
        cA = vfma(splat(o1.x), w2oA[ 4], cA); cB = vfma(splat(o1.x), w2oB[ 4], cB);
        cA = vfma(splat(o1.y), w2oA[ 5], cA); cB = vfma(splat(o1.y), w2oB[ 5], cB);
        cA = vfma(splat(o1.z), w2oA[ 6], cA); cB = vfma(splat(o1.z), w2oB[ 6], cB);
        cA = vfma(splat(o1.w), w2oA[ 7], cA); cB = vfma(splat(o1.w), w2oB[ 7], cB);
        cA = vfma(splat(o2.x), w2oA[ 8], cA); cB = vfma(splat(o2.x), w2oB[ 8], cB);
        cA = vfma(splat(o2.y), w2oA[ 9], cA); cB = vfma(splat(o2.y), w2oB[ 9], cB);
        cA = vfma(splat(o2.z), w2oA[10], cA); cB = vfma(splat(o2.z), w2oB[10], cB);
        cA = vfma(splat(o2.w), w2oA[11], cA); cB = vfma(splat(o2.w), w2oB[11], cB);
        cA = vfma(splat(o3.x), w2oA[12], cA); cB = vfma(splat(o3.x), w2oB[12], cB);
        cA = vfma(splat(o3.y), w2oA[13], cA); cB = vfma(splat(o3.y), w2oB[13], cB);
        cA = vfma(splat(o3.z), w2oA[14], cA); cB = vfma(splat(o3.z), w2oB[14], cB);
        cA = vfma(splat(o3.w), w2oA[15], cA); cB = vfma(splat(o3.w), w2oB[15], cB);

        v2f h2A = vrelu(aA + cA);            // own cols 4m, 4m+1
        v2f h2B = vrelu(aB + cB);            // own cols 4m+2, 4m+3

        // layer 3: own 4 rows -> 4 packed FMAs, then 8-lane DPP all-reduce
        v2f p = vfma(splat(h2A.x), w3r0,
                vfma(splat(h2A.y), w3r1,
                vfma(splat(h2B.x), w3r2, splat(h2B.y) * w3r3)));
        p = dpp_allreduce8(p);
        return p + b3c;
    };

    // FSAL: initial k1; thereafter k1 = accept ? k7 : k1 (bitwise exact).
    v2f k1 = f_eval(0.0f, y);

    for (int s = 0; s < MAXS; ++s) {
        float rem = T - t;
        if (!(rem > 1e-8f)) break;           // state frozen from here on
        float hs = fminf(h, rem);
        v2f hb = splat(hs);

        v2f k2 = f_eval(t + hs * 0.2f, vfma(hb, splat(0.2f) * k1, y));
        v2f k3 = f_eval(t + hs * 0.3f,
                 vfma(hb, vfma(splat((float)(3.0/40.0)), k1, splat((float)(9.0/40.0)) * k2), y));
        v2f k4 = f_eval(t + hs * 0.8f,
                 vfma(hb, vfma(splat((float)(44.0/45.0)), k1,
                          vfma(splat((float)(-56.0/15.0)), k2, splat((float)(32.0/9.0)) * k3)), y));
        v2f k5 = f_eval(t + hs * (float)(8.0/9.0),
                 vfma(hb, vfma(splat((float)(19372.0/6561.0)), k1,
                          vfma(splat((float)(-25360.0/2187.0)), k2,
                          vfma(splat((float)(64448.0/6561.0)), k3,
                               splat((float)(-212.0/729.0)) * k4))), y));
        v2f k6 = f_eval(t + hs,
                 vfma(hb, vfma(splat((float)(9017.0/3168.0)), k1,
                          vfma(splat((float)(-355.0/33.0)), k2,
                          vfma(splat((float)(46732.0/5247.0)), k3,
                          vfma(splat((float)(49.0/176.0)), k4,
                               splat((float)(-5103.0/18656.0)) * k5)))), y));
        v2f y5 = vfma(hb, vfma(splat((float)(35.0/384.0)), k1,
                          vfma(splat((float)(500.0/1113.0)), k3,
                          vfma(splat((float)(125.0/192.0)), k4,
                          vfma(splat((float)(-2187.0/6784.0)), k5,
                               splat((float)(11.0/84.0)) * k6)))), y);
        v2f k7 = f_eval(t + hs, y5);

        v2f err = hb * vfma(splat((float)(71.0/57600.0)), k1,
                       vfma(splat((float)(-71.0/16695.0)), k3,
                       vfma(splat((float)(71.0/1920.0)), k4,
                       vfma(splat((float)(-17253.0/339200.0)), k5,
                       vfma(splat((float)(22.0/525.0)), k6,
                            splat((float)(-1.0/40.0)) * k7)))));

        v2f sc = vfma(splat(0.01f),
                 __builtin_elementwise_max(__builtin_elementwise_abs(y),
                                           __builtin_elementwise_abs(y5)), splat(0.01f));
        v2f r = err / sc;
        float en = sqrtf(0.5f * (r.x * r.x + r.y * r.y));

        float fac = fminf(fmaxf(0.9f * exp2f(-0.2f * log2f(fmaxf(en, 1e-10f))), 0.2f), 10.0f);

        bool accept = (en <= 1.0f);
        if (accept) { t += hs; y = y5; }
        k1 = accept ? k7 : k1;               // FSAL (exact)
        h = hs * fac;
    }

    // final head: y @ fc_w (2x10) + fc_b; all 8 lanes hold identical y.
    out[10 * elem + m] = fmaf(y.x, fcw[m], fmaf(y.y, fcw[10 + m], fcb[m]));
    if (m < 2) {
        int c = 8 + m;
        out[10 * elem + c] = fmaf(y.x, fcw[c], fmaf(y.y, fcw[10 + c], fcb[c]));
    }
}

extern "C" void kernel_launch(void* const* d_in, const int* in_sizes, int n_in,
                              void* d_out, int out_size, void* d_ws, size_t ws_size,
                              hipStream_t stream) {
    const float* x   = (const float*)d_in[0];
    const float* sm  = (const float*)d_in[1];
    const float* w1  = (const float*)d_in[2];
    const float* b1  = (const float*)d_in[3];
    const float* w2  = (const float*)d_in[4];
    const float* b2  = (const float*)d_in[5];
    const float* w3  = (const float*)d_in[6];
    const float* b3  = (const float*)d_in[7];
    const float* fcw = (const float*)d_in[8];
    const float* fcb = (const float*)d_in[9];
    // d_in[10..15] = enc_* : dead code in the reference, unused.
    float* out = (float*)d_out;

    int n = in_sizes[1];                        // B
    const int block = 256;                      // 32 groups/block
    long long threads = (long long)n * 8;       // 8 lanes per element
    int grid = (int)((threads + block - 1) / block);   // 512 blocks
    node_kernel<<<grid, block, 0, stream>>>(x, sm, w1, b1, w2, b2, w3, b3,
                                            fcw, fcb, out, n);
}